// Round 14
// baseline (322.884 us; speedup 1.0000x reference)
//
#include <hip/hip_runtime.h>
#include <hip/hip_fp16.h>

#define N_NODES 262144
#define N_EDGES 2097152
#define EPS_BN 1e-5f
#define NBUCK 2048
#define BCAP 1280   // binomial(2M,1/2048): mean 1024, sigma 32 -> +8 sigma headroom

// Monotone float<->uint encoding: preserves order, 0 is a sentinel below everything.
__device__ __forceinline__ unsigned enc(float f) {
    unsigned u = __float_as_uint(f);
    return (u & 0x80000000u) ? ~u : (u | 0x80000000u);
}
__device__ __forceinline__ float dec(unsigned u) {
    unsigned b = (u & 0x80000000u) ? (u & 0x7FFFFFFFu) : ~u;
    return __uint_as_float(b);
}

// ---- single-kernel build: partition edges into 2048 fixed-capacity buckets ----
// bucket b = dst >> 7 (128 dsts each); entry = src | (dst&127)<<18  (src < 2^18)
__global__ __launch_bounds__(256) void part_k(const int* __restrict__ ei,
                                              int* __restrict__ bcur,
                                              unsigned* __restrict__ pairs2) {
    __shared__ int hh[NBUCK], bb[NBUCK];
    int t = threadIdx.x;
    for (int i = t; i < NBUCK; i += 256) hh[i] = 0;
    __syncthreads();
    int base = blockIdx.x * 8192;
    for (int k = 0; k < 32; ++k) {
        int d = ei[N_EDGES + base + k * 256 + t];
        atomicAdd(&hh[d >> 7], 1);
    }
    __syncthreads();
    for (int i = t; i < NBUCK; i += 256) {
        int c = hh[i];
        bb[i] = c ? atomicAdd(&bcur[i], c) : 0;
        hh[i] = 0;
    }
    __syncthreads();
    for (int k = 0; k < 32; ++k) {
        int e = base + k * 256 + t;
        int d = ei[N_EDGES + e], s = ei[e];
        int b = d >> 7;
        int r = atomicAdd(&hh[b], 1);
        int slot = bb[b] + r;
        if (slot < BCAP)   // safety clamp (statistically unreachable)
            pairs2[(size_t)b * BCAP + slot] = (unsigned)s | ((unsigned)(d & 127) << 18);
    }
}

// ---- alpha precompute: alpha[n][ch] = b1 + W1x*x_n + W1r . pos_n  (fp32) ----
__global__ __launch_bounds__(256) void alpha_k(const float* __restrict__ x,
                                               const float* __restrict__ pos,
                                               const float* __restrict__ W1,
                                               const float* __restrict__ b1,
                                               float* __restrict__ alpha) {
    int t = blockIdx.x * 256 + threadIdx.x;
    int n = t >> 4, ch = t & 15;
    float a = b1[ch] + W1[ch] * x[n]
            + W1[16 + ch] * pos[3*n] + W1[32 + ch] * pos[3*n+1] + W1[48 + ch] * pos[3*n+2];
    alpha[t] = a;
}

// ---- conv1 push: block = 1 bucket (128 dsts). 16 groups x 16 ch. agg 8 KB. ----
__global__ __launch_bounds__(256, 8) void conv1_push(
    const float* __restrict__ alpha, const float* __restrict__ pos,
    const unsigned* __restrict__ pairs2, const int* __restrict__ bcur,
    const float* __restrict__ W1,
    const float* __restrict__ mean, const float* __restrict__ var,
    const float* __restrict__ gamma, const float* __restrict__ beta_bn,
    const float* __restrict__ W2, const float* __restrict__ b2,
    __half* __restrict__ beta)
{
    __shared__ unsigned agg[128 * 16];   // 8 KB
    for (int i = threadIdx.x; i < 128 * 16; i += 256) agg[i] = 0u;
    int b = blockIdx.x;
    int cnt = min(bcur[b], BCAP);
    const unsigned* P = pairs2 + (size_t)b * BCAP;
    int g = threadIdx.x >> 4, ch = threadIdx.x & 15;
    __syncthreads();

    int e = g;
    for (; e + 112 < cnt; e += 128) {
        unsigned p[8];
        float a[8];
#pragma unroll
        for (int q = 0; q < 8; ++q) p[q] = P[e + q * 16];
#pragma unroll
        for (int q = 0; q < 8; ++q) a[q] = alpha[(p[q] & 0x3FFFFu) * 16 + ch];
#pragma unroll
        for (int q = 0; q < 8; ++q)
            atomicMax(&agg[(p[q] >> 18) * 16 + ch], enc(a[q]));
    }
    for (; e < cnt; e += 16) {
        unsigned p = P[e];
        float a = alpha[(p & 0x3FFFFu) * 16 + ch];
        atomicMax(&agg[(p >> 18) * 16 + ch], enc(a));
    }
    __syncthreads();

    // epilogue 1: agg enc -> h fp32 in place (sentinel u==0 -> no edges -> 0)
    int k = threadIdx.x & 15;
    float w1x = W1[16 + k], w1y = W1[32 + k], w1z = W1[48 + k];
    float sc1 = gamma[k] * rsqrtf(var[k] + EPS_BN);
    float sh1 = beta_bn[k] - mean[k] * sc1;
    int dbase = b * 128;
    for (int slot = threadIdx.x; slot < 2048; slot += 256) {
        int d = slot >> 4, n = dbase + d;
        unsigned u = agg[slot];
        float px = pos[3*n], py = pos[3*n+1], pz = pos[3*n+2];
        float v = u ? (dec(u) - (w1x*px + w1y*py + w1z*pz)) : 0.0f;
        ((float*)agg)[slot] = fmaxf(v * sc1 + sh1, 0.0f);
    }
    __syncthreads();

    // epilogue 2: beta[n][c] = b2 + W2h . h + W2r . pos (fp16)
    int c = threadIdx.x & 31, row = threadIdx.x >> 5;   // 8 rows
    float wc[16];
#pragma unroll
    for (int q = 0; q < 16; ++q) wc[q] = W2[q * 32 + c];
    float wxc = W2[512 + c], wyc = W2[544 + c], wzc = W2[576 + c], bc = b2[c];
    for (int d = row; d < 128; d += 8) {
        const float* h = (const float*)agg + d * 16;
        float bv = bc;
#pragma unroll
        for (int q = 0; q < 16; ++q) bv += wc[q] * h[q];
        int n = dbase + d;
        bv += wxc * pos[3*n] + wyc * pos[3*n+1] + wzc * pos[3*n+2];
        beta[(size_t)n * 32 + c] = __float2half(bv);
    }
}

// ---- conv2 push + pool: block = 1 bucket (128 dsts). 8 groups x 32 ch. 24 KB. ----
__global__ __launch_bounds__(256, 6) void conv2_push(
    const __half* __restrict__ beta, const float* __restrict__ pos,
    const unsigned* __restrict__ pairs2, const int* __restrict__ bcur,
    const float* __restrict__ W2,
    const float* __restrict__ mean, const float* __restrict__ var,
    const float* __restrict__ gamma, const float* __restrict__ beta_bn,
    unsigned* __restrict__ pool)
{
    __shared__ unsigned agg[128 * 32];   // 16 KB
    __shared__ unsigned lpool[2048];     // 8 KB
    for (int i = threadIdx.x; i < 128 * 32; i += 256) agg[i] = 0u;
    for (int i = threadIdx.x; i < 2048; i += 256) lpool[i] = 0u;
    int b = blockIdx.x;
    int cnt = min(bcur[b], BCAP);
    const unsigned* P = pairs2 + (size_t)b * BCAP;
    int g = threadIdx.x >> 5, ch = threadIdx.x & 31;
    float wrx = W2[512 + ch], wry = W2[544 + ch], wrz = W2[576 + ch];
    float sc = gamma[ch] * rsqrtf(var[ch] + EPS_BN);
    float sh = beta_bn[ch] - mean[ch] * sc;
    __syncthreads();

    int e = g;
    for (; e + 56 < cnt; e += 64) {
        unsigned p[8];
        float a[8];
#pragma unroll
        for (int q = 0; q < 8; ++q) p[q] = P[e + q * 8];
#pragma unroll
        for (int q = 0; q < 8; ++q)
            a[q] = __half2float(beta[(size_t)(p[q] & 0x3FFFFu) * 32 + ch]);
#pragma unroll
        for (int q = 0; q < 8; ++q)
            atomicMax(&agg[(p[q] >> 18) * 32 + ch], enc(a[q]));
    }
    for (; e < cnt; e += 8) {
        unsigned p = P[e];
        float a = __half2float(beta[(size_t)(p & 0x3FFFFu) * 32 + ch]);
        atomicMax(&agg[(p >> 18) * 32 + ch], enc(a));
    }
    __syncthreads();

    // epilogue: BN+ReLU + voxel pool (sentinel u==0 -> no edges -> 0)
    int dbase = b * 128;
    for (int slot = threadIdx.x; slot < 4096; slot += 256) {
        int d = slot >> 5, n = dbase + d;
        unsigned u = agg[slot];
        float px = pos[3*n], py = pos[3*n+1], pz = pos[3*n+2];
        float v = u ? (dec(u) - (wrx*px + wry*py + wrz*pz)) : 0.0f;
        float y = fmaxf(v * sc + sh, 0.0f);
        int gx = (int)floorf(px * (1.0f/16.0f));
        int gy = (int)floorf(py * (1.0f/16.0f));
        int cl = min(max(gx + gy * 8, 0), 63);
        atomicMax(&lpool[cl * 32 + ch], enc(y));
    }
    __syncthreads();
    for (int i = threadIdx.x; i < 2048; i += 256) {
        unsigned u = lpool[i];
        if (u > pool[i]) atomicMax(&pool[i], u);
    }
}

__global__ __launch_bounds__(256) void pool_decode(const unsigned* __restrict__ pool,
                                                   float* __restrict__ out) {
    int i = blockIdx.x * 256 + threadIdx.x;   // 2048
    unsigned u = pool[i];
    out[i] = (u == 0u) ? 0.0f : dec(u);
}

extern "C" void kernel_launch(void* const* d_in, const int* in_sizes, int n_in,
                              void* d_out, int out_size, void* d_ws, size_t ws_size,
                              hipStream_t stream) {
    const float* x    = (const float*)d_in[0];
    const float* pos  = (const float*)d_in[1];
    const int*   ei   = (const int*)d_in[2];
    const float* W1   = (const float*)d_in[3];
    const float* b1   = (const float*)d_in[4];
    const float* bn1m = (const float*)d_in[5];
    const float* bn1v = (const float*)d_in[6];
    const float* bn1w = (const float*)d_in[7];
    const float* bn1b = (const float*)d_in[8];
    const float* W2   = (const float*)d_in[9];
    const float* b2   = (const float*)d_in[10];
    const float* bn2m = (const float*)d_in[11];
    const float* bn2v = (const float*)d_in[12];
    const float* bn2w = (const float*)d_in[13];
    const float* bn2b = (const float*)d_in[14];

    size_t N = N_NODES;
    unsigned* pool   = (unsigned*)d_ws;                   // 2048 [zeroed]
    int* bcur        = (int*)(pool + 2048);               // NBUCK [zeroed]
    unsigned* pairs2 = (unsigned*)(bcur + NBUCK);         // NBUCK*BCAP = 2.62M words
    float* alpha     = (float*)(pairs2 + (size_t)NBUCK * BCAP); // 16N fp32
    __half* beta     = (__half*)(alpha + 16 * N);         // 32N fp16 = 16N words

    hipMemsetAsync(d_ws, 0, (size_t)(2048 + NBUCK) * 4, stream);

    part_k      <<<N_EDGES/8192, 256, 0, stream>>>(ei, bcur, pairs2);
    alpha_k     <<<N_NODES*16/256, 256, 0, stream>>>(x, pos, W1, b1, alpha);
    conv1_push  <<<NBUCK, 256, 0, stream>>>(alpha, pos, pairs2, bcur,
                                            W1, bn1m, bn1v, bn1w, bn1b, W2, b2, beta);
    conv2_push  <<<NBUCK, 256, 0, stream>>>(beta, pos, pairs2, bcur,
                                            W2, bn2m, bn2v, bn2w, bn2b, pool);
    pool_decode <<<8, 256, 0, stream>>>(pool, (float*)d_out);
}

// Round 15
// 289.562 us; speedup vs baseline: 1.1151x; 1.1151x over previous
//
#include <hip/hip_runtime.h>
#include <hip/hip_fp16.h>

#define N_NODES 262144
#define N_EDGES 2097152
#define EPS_BN 1e-5f
#define NBUCK 2048
#define BCAP 1280   // binomial(2M,1/2048): mean 1024, sigma 32 -> +8 sigma headroom

// Monotone float<->uint encoding: preserves order, 0 is a sentinel below everything.
__device__ __forceinline__ unsigned enc(float f) {
    unsigned u = __float_as_uint(f);
    return (u & 0x80000000u) ? ~u : (u | 0x80000000u);
}
__device__ __forceinline__ float dec(unsigned u) {
    unsigned b = (u & 0x80000000u) ? (u & 0x7FFFFFFFu) : ~u;
    return __uint_as_float(b);
}

// ---- single-kernel build: partition edges into 2048 fixed-capacity buckets ----
// bucket b = dst >> 7 (128 dsts each); entry = src | (dst&127)<<18  (src < 2^18)
__global__ __launch_bounds__(256) void part_k(const int* __restrict__ ei,
                                              int* __restrict__ bcur,
                                              unsigned* __restrict__ pairs2) {
    __shared__ int hh[NBUCK], bb[NBUCK];
    int t = threadIdx.x;
    for (int i = t; i < NBUCK; i += 256) hh[i] = 0;
    __syncthreads();
    int base = blockIdx.x * 8192;
    for (int k = 0; k < 32; ++k) {
        int d = ei[N_EDGES + base + k * 256 + t];
        atomicAdd(&hh[d >> 7], 1);
    }
    __syncthreads();
    for (int i = t; i < NBUCK; i += 256) {
        int c = hh[i];
        bb[i] = c ? atomicAdd(&bcur[i], c) : 0;
        hh[i] = 0;
    }
    __syncthreads();
    for (int k = 0; k < 32; ++k) {
        int e = base + k * 256 + t;
        int d = ei[N_EDGES + e], s = ei[e];
        int b = d >> 7;
        int r = atomicAdd(&hh[b], 1);
        int slot = bb[b] + r;
        if (slot < BCAP)   // safety clamp (statistically unreachable)
            pairs2[(size_t)b * BCAP + slot] = (unsigned)s | ((unsigned)(d & 127) << 18);
    }
}

// ---- alpha precompute: alpha[n][ch] = b1 + W1x*x_n + W1r . pos_n  (fp32) ----
__global__ __launch_bounds__(256) void alpha_k(const float* __restrict__ x,
                                               const float* __restrict__ pos,
                                               const float* __restrict__ W1,
                                               const float* __restrict__ b1,
                                               float* __restrict__ alpha) {
    int t = blockIdx.x * 256 + threadIdx.x;
    int n = t >> 4, ch = t & 15;
    float a = b1[ch] + W1[ch] * x[n]
            + W1[16 + ch] * pos[3*n] + W1[32 + ch] * pos[3*n+1] + W1[48 + ch] * pos[3*n+2];
    alpha[t] = a;
}

// ---- conv1 push: block = 1 bucket (128 dsts). 16 groups x 16 ch. agg 8 KB. ----
// (256,6): VGPR cap ~85 — unroll-8 pipeline needs ~55; (256,8)'s cap of 32 spilled (r14).
__global__ __launch_bounds__(256, 6) void conv1_push(
    const float* __restrict__ alpha, const float* __restrict__ pos,
    const unsigned* __restrict__ pairs2, const int* __restrict__ bcur,
    const float* __restrict__ W1,
    const float* __restrict__ mean, const float* __restrict__ var,
    const float* __restrict__ gamma, const float* __restrict__ beta_bn,
    const float* __restrict__ W2, const float* __restrict__ b2,
    __half* __restrict__ beta)
{
    __shared__ unsigned agg[128 * 16];   // 8 KB
    for (int i = threadIdx.x; i < 128 * 16; i += 256) agg[i] = 0u;
    int b = blockIdx.x;
    int cnt = min(bcur[b], BCAP);
    const unsigned* P = pairs2 + (size_t)b * BCAP;
    int g = threadIdx.x >> 4, ch = threadIdx.x & 15;
    __syncthreads();

    int e = g;
    for (; e + 112 < cnt; e += 128) {
        unsigned p[8];
        float a[8];
#pragma unroll
        for (int q = 0; q < 8; ++q) p[q] = P[e + q * 16];
#pragma unroll
        for (int q = 0; q < 8; ++q) a[q] = alpha[(p[q] & 0x3FFFFu) * 16 + ch];
#pragma unroll
        for (int q = 0; q < 8; ++q)
            atomicMax(&agg[(p[q] >> 18) * 16 + ch], enc(a[q]));
    }
    for (; e < cnt; e += 16) {
        unsigned p = P[e];
        float a = alpha[(p & 0x3FFFFu) * 16 + ch];
        atomicMax(&agg[(p >> 18) * 16 + ch], enc(a));
    }
    __syncthreads();

    // epilogue 1: agg enc -> h fp32 in place (sentinel u==0 -> no edges -> 0)
    int k = threadIdx.x & 15;
    float w1x = W1[16 + k], w1y = W1[32 + k], w1z = W1[48 + k];
    float sc1 = gamma[k] * rsqrtf(var[k] + EPS_BN);
    float sh1 = beta_bn[k] - mean[k] * sc1;
    int dbase = b * 128;
    for (int slot = threadIdx.x; slot < 2048; slot += 256) {
        int d = slot >> 4, n = dbase + d;
        unsigned u = agg[slot];
        float px = pos[3*n], py = pos[3*n+1], pz = pos[3*n+2];
        float v = u ? (dec(u) - (w1x*px + w1y*py + w1z*pz)) : 0.0f;
        ((float*)agg)[slot] = fmaxf(v * sc1 + sh1, 0.0f);
    }
    __syncthreads();

    // epilogue 2: beta[n][c] = b2 + W2h . h + W2r . pos (fp16)
    int c = threadIdx.x & 31, row = threadIdx.x >> 5;   // 8 rows
    float wc[16];
#pragma unroll
    for (int q = 0; q < 16; ++q) wc[q] = W2[q * 32 + c];
    float wxc = W2[512 + c], wyc = W2[544 + c], wzc = W2[576 + c], bc = b2[c];
    for (int d = row; d < 128; d += 8) {
        const float* h = (const float*)agg + d * 16;
        float bv = bc;
#pragma unroll
        for (int q = 0; q < 16; ++q) bv += wc[q] * h[q];
        int n = dbase + d;
        bv += wxc * pos[3*n] + wyc * pos[3*n+1] + wzc * pos[3*n+2];
        beta[(size_t)n * 32 + c] = __float2half(bv);
    }
}

// ---- conv2 push + pool: block = 1 bucket (128 dsts). 8 groups x 32 ch. 24 KB. ----
__global__ __launch_bounds__(256, 6) void conv2_push(
    const __half* __restrict__ beta, const float* __restrict__ pos,
    const unsigned* __restrict__ pairs2, const int* __restrict__ bcur,
    const float* __restrict__ W2,
    const float* __restrict__ mean, const float* __restrict__ var,
    const float* __restrict__ gamma, const float* __restrict__ beta_bn,
    unsigned* __restrict__ pool)
{
    __shared__ unsigned agg[128 * 32];   // 16 KB
    __shared__ unsigned lpool[2048];     // 8 KB
    for (int i = threadIdx.x; i < 128 * 32; i += 256) agg[i] = 0u;
    for (int i = threadIdx.x; i < 2048; i += 256) lpool[i] = 0u;
    int b = blockIdx.x;
    int cnt = min(bcur[b], BCAP);
    const unsigned* P = pairs2 + (size_t)b * BCAP;
    int g = threadIdx.x >> 5, ch = threadIdx.x & 31;
    float wrx = W2[512 + ch], wry = W2[544 + ch], wrz = W2[576 + ch];
    float sc = gamma[ch] * rsqrtf(var[ch] + EPS_BN);
    float sh = beta_bn[ch] - mean[ch] * sc;
    __syncthreads();

    int e = g;
    for (; e + 56 < cnt; e += 64) {
        unsigned p[8];
        float a[8];
#pragma unroll
        for (int q = 0; q < 8; ++q) p[q] = P[e + q * 8];
#pragma unroll
        for (int q = 0; q < 8; ++q)
            a[q] = __half2float(beta[(size_t)(p[q] & 0x3FFFFu) * 32 + ch]);
#pragma unroll
        for (int q = 0; q < 8; ++q)
            atomicMax(&agg[(p[q] >> 18) * 32 + ch], enc(a[q]));
    }
    for (; e < cnt; e += 8) {
        unsigned p = P[e];
        float a = __half2float(beta[(size_t)(p & 0x3FFFFu) * 32 + ch]);
        atomicMax(&agg[(p >> 18) * 32 + ch], enc(a));
    }
    __syncthreads();

    // epilogue: BN+ReLU + voxel pool (sentinel u==0 -> no edges -> 0)
    int dbase = b * 128;
    for (int slot = threadIdx.x; slot < 4096; slot += 256) {
        int d = slot >> 5, n = dbase + d;
        unsigned u = agg[slot];
        float px = pos[3*n], py = pos[3*n+1], pz = pos[3*n+2];
        float v = u ? (dec(u) - (wrx*px + wry*py + wrz*pz)) : 0.0f;
        float y = fmaxf(v * sc + sh, 0.0f);
        int gx = (int)floorf(px * (1.0f/16.0f));
        int gy = (int)floorf(py * (1.0f/16.0f));
        int cl = min(max(gx + gy * 8, 0), 63);
        atomicMax(&lpool[cl * 32 + ch], enc(y));
    }
    __syncthreads();
    for (int i = threadIdx.x; i < 2048; i += 256) {
        unsigned u = lpool[i];
        if (u > pool[i]) atomicMax(&pool[i], u);
    }
}

__global__ __launch_bounds__(256) void pool_decode(const unsigned* __restrict__ pool,
                                                   float* __restrict__ out) {
    int i = blockIdx.x * 256 + threadIdx.x;   // 2048
    unsigned u = pool[i];
    out[i] = (u == 0u) ? 0.0f : dec(u);
}

extern "C" void kernel_launch(void* const* d_in, const int* in_sizes, int n_in,
                              void* d_out, int out_size, void* d_ws, size_t ws_size,
                              hipStream_t stream) {
    const float* x    = (const float*)d_in[0];
    const float* pos  = (const float*)d_in[1];
    const int*   ei   = (const int*)d_in[2];
    const float* W1   = (const float*)d_in[3];
    const float* b1   = (const float*)d_in[4];
    const float* bn1m = (const float*)d_in[5];
    const float* bn1v = (const float*)d_in[6];
    const float* bn1w = (const float*)d_in[7];
    const float* bn1b = (const float*)d_in[8];
    const float* W2   = (const float*)d_in[9];
    const float* b2   = (const float*)d_in[10];
    const float* bn2m = (const float*)d_in[11];
    const float* bn2v = (const float*)d_in[12];
    const float* bn2w = (const float*)d_in[13];
    const float* bn2b = (const float*)d_in[14];

    size_t N = N_NODES;
    unsigned* pool   = (unsigned*)d_ws;                   // 2048 [zeroed]
    int* bcur        = (int*)(pool + 2048);               // NBUCK [zeroed]
    unsigned* pairs2 = (unsigned*)(bcur + NBUCK);         // NBUCK*BCAP = 2.62M words
    float* alpha     = (float*)(pairs2 + (size_t)NBUCK * BCAP); // 16N fp32
    __half* beta     = (__half*)(alpha + 16 * N);         // 32N fp16 = 16N words

    hipMemsetAsync(d_ws, 0, (size_t)(2048 + NBUCK) * 4, stream);

    part_k      <<<N_EDGES/8192, 256, 0, stream>>>(ei, bcur, pairs2);
    alpha_k     <<<N_NODES*16/256, 256, 0, stream>>>(x, pos, W1, b1, alpha);
    conv1_push  <<<NBUCK, 256, 0, stream>>>(alpha, pos, pairs2, bcur,
                                            W1, bn1m, bn1v, bn1w, bn1b, W2, b2, beta);
    conv2_push  <<<NBUCK, 256, 0, stream>>>(beta, pos, pairs2, bcur,
                                            W2, bn2m, bn2v, bn2w, bn2b, pool);
    pool_decode <<<8, 256, 0, stream>>>(pool, (float*)d_out);
}

// Round 16
// 265.089 us; speedup vs baseline: 1.2180x; 1.0923x over previous
//
#include <hip/hip_runtime.h>
#include <hip/hip_fp16.h>

#define N_NODES 262144
#define N_EDGES 2097152
#define EPS_BN 1e-5f
#define NBUCK 1024
#define BCAP 2560   // binomial(2M,1/1024): mean 2048, sigma 45 -> +11 sigma headroom

// Monotone float<->uint encoding: preserves order, 0 is a sentinel below everything.
__device__ __forceinline__ unsigned enc(float f) {
    unsigned u = __float_as_uint(f);
    return (u & 0x80000000u) ? ~u : (u | 0x80000000u);
}
__device__ __forceinline__ float dec(unsigned u) {
    unsigned b = (u & 0x80000000u) ? (u & 0x7FFFFFFFu) : ~u;
    return __uint_as_float(b);
}

// ---- single-kernel build: partition edges into 1024 fixed-capacity buckets ----
// bucket b = dst >> 8 (256 dsts each); entry = src | (dst&255)<<18  (src < 2^18)
__global__ __launch_bounds__(256) void part_k(const int* __restrict__ ei,
                                              int* __restrict__ bcur,
                                              unsigned* __restrict__ pairs2) {
    __shared__ int hh[NBUCK], bb[NBUCK];
    int t = threadIdx.x;
    for (int i = t; i < NBUCK; i += 256) hh[i] = 0;
    __syncthreads();
    int base = blockIdx.x * 4096;
    for (int k = 0; k < 16; ++k) {
        int d = ei[N_EDGES + base + k * 256 + t];
        atomicAdd(&hh[d >> 8], 1);
    }
    __syncthreads();
    for (int i = t; i < NBUCK; i += 256) {
        int c = hh[i];
        bb[i] = c ? atomicAdd(&bcur[i], c) : 0;
        hh[i] = 0;
    }
    __syncthreads();
    for (int k = 0; k < 16; ++k) {
        int e = base + k * 256 + t;
        int d = ei[N_EDGES + e], s = ei[e];
        int b = d >> 8;
        int r = atomicAdd(&hh[b], 1);
        int slot = bb[b] + r;
        if (slot < BCAP)   // safety clamp (statistically unreachable)
            pairs2[(size_t)b * BCAP + slot] = (unsigned)s | ((unsigned)(d & 255) << 18);
    }
}

// ---- pack [pos3, x] per node: 4 MB table, fits each XCD's 4 MB L2 ----
__global__ __launch_bounds__(256) void pack_px(const float* __restrict__ pos,
                                               const float* __restrict__ x,
                                               float4* __restrict__ px4) {
    int i = blockIdx.x * 256 + threadIdx.x;
    px4[i] = make_float4(pos[3*i], pos[3*i+1], pos[3*i+2], x[i]);
}

// ---- conv1 push: block = 1 bucket (256 dsts). 16 groups x 16 ch. agg 16 KB. ----
// Gathers 16-B px4 rows (L2-resident table) and computes alpha in-lane.
__global__ __launch_bounds__(256) void conv1_push(
    const float4* __restrict__ px4, const float* __restrict__ pos,
    const unsigned* __restrict__ pairs2, const int* __restrict__ bcur,
    const float* __restrict__ W1, const float* __restrict__ b1,
    const float* __restrict__ mean, const float* __restrict__ var,
    const float* __restrict__ gamma, const float* __restrict__ beta_bn,
    const float* __restrict__ W2, const float* __restrict__ b2,
    __half* __restrict__ beta)
{
    __shared__ unsigned agg[256 * 16];   // 16 KB
    for (int i = threadIdx.x; i < 256 * 16; i += 256) agg[i] = 0u;
    int b = blockIdx.x;
    int cnt = min(bcur[b], BCAP);
    const unsigned* P = pairs2 + (size_t)b * BCAP;
    int g = threadIdx.x >> 4, ch = threadIdx.x & 15;
    // per-lane W1 column: alpha_j = b1 + w1x*x_j + wr . pos_j
    float w1xc = W1[ch], wrx = W1[16 + ch], wry = W1[32 + ch], wrz = W1[48 + ch];
    float b1c = b1[ch];
    __syncthreads();

    int e = g;
    for (; e + 48 < cnt; e += 64) {
        unsigned p0 = P[e], p1 = P[e+16], p2 = P[e+32], p3 = P[e+48];
        float4 q0 = px4[p0 & 0x3FFFFu];
        float4 q1 = px4[p1 & 0x3FFFFu];
        float4 q2 = px4[p2 & 0x3FFFFu];
        float4 q3 = px4[p3 & 0x3FFFFu];
        float a0 = b1c + w1xc*q0.w + wrx*q0.x + wry*q0.y + wrz*q0.z;
        float a1 = b1c + w1xc*q1.w + wrx*q1.x + wry*q1.y + wrz*q1.z;
        float a2 = b1c + w1xc*q2.w + wrx*q2.x + wry*q2.y + wrz*q2.z;
        float a3 = b1c + w1xc*q3.w + wrx*q3.x + wry*q3.y + wrz*q3.z;
        atomicMax(&agg[(p0 >> 18) * 16 + ch], enc(a0));
        atomicMax(&agg[(p1 >> 18) * 16 + ch], enc(a1));
        atomicMax(&agg[(p2 >> 18) * 16 + ch], enc(a2));
        atomicMax(&agg[(p3 >> 18) * 16 + ch], enc(a3));
    }
    for (; e < cnt; e += 16) {
        unsigned p = P[e];
        float4 q = px4[p & 0x3FFFFu];
        float a = b1c + w1xc*q.w + wrx*q.x + wry*q.y + wrz*q.z;
        atomicMax(&agg[(p >> 18) * 16 + ch], enc(a));
    }
    __syncthreads();

    // epilogue 1: agg enc -> h fp32 in place (sentinel u==0 -> no edges -> 0)
    float sc1 = gamma[ch] * rsqrtf(var[ch] + EPS_BN);
    float sh1 = beta_bn[ch] - mean[ch] * sc1;
    int dbase = b * 256;
    for (int slot = threadIdx.x; slot < 4096; slot += 256) {
        int d = slot >> 4, n = dbase + d;
        unsigned u = agg[slot];
        float px = pos[3*n], py = pos[3*n+1], pz = pos[3*n+2];
        float v = u ? (dec(u) - (wrx*px + wry*py + wrz*pz)) : 0.0f;
        ((float*)agg)[slot] = fmaxf(v * sc1 + sh1, 0.0f);
    }
    __syncthreads();

    // epilogue 2: beta[n][c] = b2 + W2h . h + W2r . pos (fp16)
    int c = threadIdx.x & 31, row = threadIdx.x >> 5;   // 8 rows
    float wc[16];
#pragma unroll
    for (int q = 0; q < 16; ++q) wc[q] = W2[q * 32 + c];
    float wxc = W2[512 + c], wyc = W2[544 + c], wzc = W2[576 + c], bc = b2[c];
    for (int d = row; d < 256; d += 8) {
        const float* h = (const float*)agg + d * 16;
        float bv = bc;
#pragma unroll
        for (int q = 0; q < 16; ++q) bv += wc[q] * h[q];
        int n = dbase + d;
        bv += wxc * pos[3*n] + wyc * pos[3*n+1] + wzc * pos[3*n+2];
        beta[(size_t)n * 32 + c] = __float2half(bv);
    }
}

// ---- conv2 push + pool: block = 1 bucket (256 dsts). 8 groups x 32 ch. 40 KB. ----
__global__ __launch_bounds__(256) void conv2_push(
    const __half* __restrict__ beta, const float* __restrict__ pos,
    const unsigned* __restrict__ pairs2, const int* __restrict__ bcur,
    const float* __restrict__ W2,
    const float* __restrict__ mean, const float* __restrict__ var,
    const float* __restrict__ gamma, const float* __restrict__ beta_bn,
    unsigned* __restrict__ pool)
{
    __shared__ unsigned agg[256 * 32];   // 32 KB
    __shared__ unsigned lpool[2048];     // 8 KB
    for (int i = threadIdx.x; i < 256 * 32; i += 256) agg[i] = 0u;
    for (int i = threadIdx.x; i < 2048; i += 256) lpool[i] = 0u;
    int b = blockIdx.x;
    int cnt = min(bcur[b], BCAP);
    const unsigned* P = pairs2 + (size_t)b * BCAP;
    int g = threadIdx.x >> 5, ch = threadIdx.x & 31;
    float wrx = W2[512 + ch], wry = W2[544 + ch], wrz = W2[576 + ch];
    float sc = gamma[ch] * rsqrtf(var[ch] + EPS_BN);
    float sh = beta_bn[ch] - mean[ch] * sc;
    __syncthreads();

    int e = g;
    for (; e + 24 < cnt; e += 32) {
        unsigned p0 = P[e], p1 = P[e+8], p2 = P[e+16], p3 = P[e+24];
        float a0 = __half2float(beta[(size_t)(p0 & 0x3FFFFu) * 32 + ch]);
        float a1 = __half2float(beta[(size_t)(p1 & 0x3FFFFu) * 32 + ch]);
        float a2 = __half2float(beta[(size_t)(p2 & 0x3FFFFu) * 32 + ch]);
        float a3 = __half2float(beta[(size_t)(p3 & 0x3FFFFu) * 32 + ch]);
        atomicMax(&agg[(p0 >> 18) * 32 + ch], enc(a0));
        atomicMax(&agg[(p1 >> 18) * 32 + ch], enc(a1));
        atomicMax(&agg[(p2 >> 18) * 32 + ch], enc(a2));
        atomicMax(&agg[(p3 >> 18) * 32 + ch], enc(a3));
    }
    for (; e < cnt; e += 8) {
        unsigned p = P[e];
        float a = __half2float(beta[(size_t)(p & 0x3FFFFu) * 32 + ch]);
        atomicMax(&agg[(p >> 18) * 32 + ch], enc(a));
    }
    __syncthreads();

    // epilogue: BN+ReLU + voxel pool (sentinel u==0 -> no edges -> 0)
    int dbase = b * 256;
    for (int slot = threadIdx.x; slot < 8192; slot += 256) {
        int d = slot >> 5, n = dbase + d;
        unsigned u = agg[slot];
        float px = pos[3*n], py = pos[3*n+1], pz = pos[3*n+2];
        float v = u ? (dec(u) - (wrx*px + wry*py + wrz*pz)) : 0.0f;
        float y = fmaxf(v * sc + sh, 0.0f);
        int gx = (int)floorf(px * (1.0f/16.0f));
        int gy = (int)floorf(py * (1.0f/16.0f));
        int cl = min(max(gx + gy * 8, 0), 63);
        atomicMax(&lpool[cl * 32 + ch], enc(y));
    }
    __syncthreads();
    for (int i = threadIdx.x; i < 2048; i += 256) {
        unsigned u = lpool[i];
        if (u > pool[i]) atomicMax(&pool[i], u);
    }
}

__global__ __launch_bounds__(256) void pool_decode(const unsigned* __restrict__ pool,
                                                   float* __restrict__ out) {
    int i = blockIdx.x * 256 + threadIdx.x;   // 2048
    unsigned u = pool[i];
    out[i] = (u == 0u) ? 0.0f : dec(u);
}

extern "C" void kernel_launch(void* const* d_in, const int* in_sizes, int n_in,
                              void* d_out, int out_size, void* d_ws, size_t ws_size,
                              hipStream_t stream) {
    const float* x    = (const float*)d_in[0];
    const float* pos  = (const float*)d_in[1];
    const int*   ei   = (const int*)d_in[2];
    const float* W1   = (const float*)d_in[3];
    const float* b1   = (const float*)d_in[4];
    const float* bn1m = (const float*)d_in[5];
    const float* bn1v = (const float*)d_in[6];
    const float* bn1w = (const float*)d_in[7];
    const float* bn1b = (const float*)d_in[8];
    const float* W2   = (const float*)d_in[9];
    const float* b2   = (const float*)d_in[10];
    const float* bn2m = (const float*)d_in[11];
    const float* bn2v = (const float*)d_in[12];
    const float* bn2w = (const float*)d_in[13];
    const float* bn2b = (const float*)d_in[14];

    size_t N = N_NODES;
    unsigned* pool   = (unsigned*)d_ws;                   // 2048 [zeroed]
    int* bcur        = (int*)(pool + 2048);               // NBUCK [zeroed]
    unsigned* pairs2 = (unsigned*)(bcur + NBUCK);         // NBUCK*BCAP = 2.62M words
    float* px4       = (float*)(pairs2 + (size_t)NBUCK * BCAP); // 4N fp32 (4 MB)
    __half* beta     = (__half*)(px4 + 4 * N);            // 32N fp16 = 16N words

    hipMemsetAsync(d_ws, 0, (size_t)(2048 + NBUCK) * 4, stream);

    part_k      <<<N_EDGES/4096, 256, 0, stream>>>(ei, bcur, pairs2);
    pack_px     <<<N_NODES/256, 256, 0, stream>>>(pos, x, (float4*)px4);
    conv1_push  <<<NBUCK, 256, 0, stream>>>((const float4*)px4, pos, pairs2, bcur,
                                            W1, b1, bn1m, bn1v, bn1w, bn1b, W2, b2, beta);
    conv2_push  <<<NBUCK, 256, 0, stream>>>(beta, pos, pairs2, bcur,
                                            W2, bn2m, bn2v, bn2w, bn2b, pool);
    pool_decode <<<8, 256, 0, stream>>>(pool, (float*)d_out);
}

// Round 17
// 252.734 us; speedup vs baseline: 1.2776x; 1.0489x over previous
//
#include <hip/hip_runtime.h>
#include <hip/hip_fp16.h>

#define N_NODES 262144
#define N_EDGES 2097152
#define EPS_BN 1e-5f
#define NBUCK 1024
#define BCAP 2560   // binomial(2M,1/1024): mean 2048, sigma 45 -> +11 sigma headroom
#define PARTB 256   // part_k blocks; 8192 edges each

// Monotone float<->uint encoding: preserves order, 0 is a sentinel below everything.
__device__ __forceinline__ unsigned enc(float f) {
    unsigned u = __float_as_uint(f);
    return (u & 0x80000000u) ? ~u : (u | 0x80000000u);
}
__device__ __forceinline__ float dec(unsigned u) {
    unsigned b = (u & 0x80000000u) ? (u & 0x7FFFFFFFu) : ~u;
    return __uint_as_float(b);
}

// ---- single-kernel build: partition edges into 1024 fixed-capacity buckets,
// fused with px4 packing. bucket b = dst >> 8; entry = src | (dst&255)<<18.
__global__ __launch_bounds__(256) void part_k(const int* __restrict__ ei,
                                              int* __restrict__ bcur,
                                              unsigned* __restrict__ pairs2,
                                              const float* __restrict__ pos,
                                              const float* __restrict__ x,
                                              float4* __restrict__ px4) {
    __shared__ int hh[NBUCK], bb[NBUCK];
    int t = threadIdx.x;
    for (int i = t; i < NBUCK; i += 256) hh[i] = 0;
    __syncthreads();
    int base = blockIdx.x * (N_EDGES / PARTB);
    for (int k = 0; k < N_EDGES / PARTB / 256; ++k) {   // 32
        int d = ei[N_EDGES + base + k * 256 + t];
        atomicAdd(&hh[d >> 8], 1);
    }
    __syncthreads();
    for (int i = t; i < NBUCK; i += 256) {
        int c = hh[i];
        bb[i] = c ? atomicAdd(&bcur[i], c) : 0;
        hh[i] = 0;
    }
    __syncthreads();
    for (int k = 0; k < N_EDGES / PARTB / 256; ++k) {
        int e = base + k * 256 + t;
        int d = ei[N_EDGES + e], s = ei[e];
        int b = d >> 8;
        int r = atomicAdd(&hh[b], 1);
        int slot = bb[b] + r;
        if (slot < BCAP)   // safety clamp (statistically unreachable)
            pairs2[(size_t)b * BCAP + slot] = (unsigned)s | ((unsigned)(d & 255) << 18);
    }
    // fused pack: [pos3, x] rows for conv1's L2-resident gather table (1024 nodes/block)
    int nb = blockIdx.x * (N_NODES / PARTB);
    for (int i = t; i < N_NODES / PARTB; i += 256) {
        int n = nb + i;
        px4[n] = make_float4(pos[3*n], pos[3*n+1], pos[3*n+2], x[n]);
    }
}

// ---- conv1 push: block = 1 bucket (256 dsts). 16 groups x 16 ch. agg 16 KB. ----
// Gathers 16-B px4 rows (L2-resident table) and computes alpha in-lane.
__global__ __launch_bounds__(256) void conv1_push(
    const float4* __restrict__ px4, const float* __restrict__ pos,
    const unsigned* __restrict__ pairs2, const int* __restrict__ bcur,
    const float* __restrict__ W1, const float* __restrict__ b1,
    const float* __restrict__ mean, const float* __restrict__ var,
    const float* __restrict__ gamma, const float* __restrict__ beta_bn,
    const float* __restrict__ W2, const float* __restrict__ b2,
    __half* __restrict__ beta)
{
    __shared__ unsigned agg[256 * 16];   // 16 KB
    for (int i = threadIdx.x; i < 256 * 16; i += 256) agg[i] = 0u;
    int b = blockIdx.x;
    int cnt = min(bcur[b], BCAP);
    const unsigned* P = pairs2 + (size_t)b * BCAP;
    int g = threadIdx.x >> 4, ch = threadIdx.x & 15;
    // per-lane W1 column: alpha_j = b1 + w1x*x_j + wr . pos_j
    float w1xc = W1[ch], wrx = W1[16 + ch], wry = W1[32 + ch], wrz = W1[48 + ch];
    float b1c = b1[ch];
    __syncthreads();

    int e = g;
    for (; e + 48 < cnt; e += 64) {
        unsigned p0 = P[e], p1 = P[e+16], p2 = P[e+32], p3 = P[e+48];
        float4 q0 = px4[p0 & 0x3FFFFu];
        float4 q1 = px4[p1 & 0x3FFFFu];
        float4 q2 = px4[p2 & 0x3FFFFu];
        float4 q3 = px4[p3 & 0x3FFFFu];
        float a0 = b1c + w1xc*q0.w + wrx*q0.x + wry*q0.y + wrz*q0.z;
        float a1 = b1c + w1xc*q1.w + wrx*q1.x + wry*q1.y + wrz*q1.z;
        float a2 = b1c + w1xc*q2.w + wrx*q2.x + wry*q2.y + wrz*q2.z;
        float a3 = b1c + w1xc*q3.w + wrx*q3.x + wry*q3.y + wrz*q3.z;
        atomicMax(&agg[(p0 >> 18) * 16 + ch], enc(a0));
        atomicMax(&agg[(p1 >> 18) * 16 + ch], enc(a1));
        atomicMax(&agg[(p2 >> 18) * 16 + ch], enc(a2));
        atomicMax(&agg[(p3 >> 18) * 16 + ch], enc(a3));
    }
    for (; e < cnt; e += 16) {
        unsigned p = P[e];
        float4 q = px4[p & 0x3FFFFu];
        float a = b1c + w1xc*q.w + wrx*q.x + wry*q.y + wrz*q.z;
        atomicMax(&agg[(p >> 18) * 16 + ch], enc(a));
    }
    __syncthreads();

    // epilogue 1: agg enc -> h fp32 in place (sentinel u==0 -> no edges -> 0)
    float sc1 = gamma[ch] * rsqrtf(var[ch] + EPS_BN);
    float sh1 = beta_bn[ch] - mean[ch] * sc1;
    int dbase = b * 256;
    for (int slot = threadIdx.x; slot < 4096; slot += 256) {
        int d = slot >> 4, n = dbase + d;
        unsigned u = agg[slot];
        float px = pos[3*n], py = pos[3*n+1], pz = pos[3*n+2];
        float v = u ? (dec(u) - (wrx*px + wry*py + wrz*pz)) : 0.0f;
        ((float*)agg)[slot] = fmaxf(v * sc1 + sh1, 0.0f);
    }
    __syncthreads();

    // epilogue 2: beta[n][c] = b2 + W2h . h + W2r . pos (fp16)
    int c = threadIdx.x & 31, row = threadIdx.x >> 5;   // 8 rows
    float wc[16];
#pragma unroll
    for (int q = 0; q < 16; ++q) wc[q] = W2[q * 32 + c];
    float wxc = W2[512 + c], wyc = W2[544 + c], wzc = W2[576 + c], bc = b2[c];
    for (int d = row; d < 256; d += 8) {
        const float* h = (const float*)agg + d * 16;
        float bv = bc;
#pragma unroll
        for (int q = 0; q < 16; ++q) bv += wc[q] * h[q];
        int n = dbase + d;
        bv += wxc * pos[3*n] + wyc * pos[3*n+1] + wzc * pos[3*n+2];
        beta[(size_t)n * 32 + c] = __float2half(bv);
    }
}

// ---- conv2 push + pool: block = 1 bucket (256 dsts). 8 groups x 32 ch. 40 KB. ----
// (256,6): unroll-8 pipeline needs ~55 VGPR; tighter caps spill (r12/r14 evidence).
__global__ __launch_bounds__(256, 6) void conv2_push(
    const __half* __restrict__ beta, const float* __restrict__ pos,
    const unsigned* __restrict__ pairs2, const int* __restrict__ bcur,
    const float* __restrict__ W2,
    const float* __restrict__ mean, const float* __restrict__ var,
    const float* __restrict__ gamma, const float* __restrict__ beta_bn,
    unsigned* __restrict__ pool)
{
    __shared__ unsigned agg[256 * 32];   // 32 KB
    __shared__ unsigned lpool[2048];     // 8 KB
    for (int i = threadIdx.x; i < 256 * 32; i += 256) agg[i] = 0u;
    for (int i = threadIdx.x; i < 2048; i += 256) lpool[i] = 0u;
    int b = blockIdx.x;
    int cnt = min(bcur[b], BCAP);
    const unsigned* P = pairs2 + (size_t)b * BCAP;
    int g = threadIdx.x >> 5, ch = threadIdx.x & 31;
    float wrx = W2[512 + ch], wry = W2[544 + ch], wrz = W2[576 + ch];
    float sc = gamma[ch] * rsqrtf(var[ch] + EPS_BN);
    float sh = beta_bn[ch] - mean[ch] * sc;
    __syncthreads();

    int e = g;
    for (; e + 56 < cnt; e += 64) {
        unsigned p[8];
        float a[8];
#pragma unroll
        for (int q = 0; q < 8; ++q) p[q] = P[e + q * 8];
#pragma unroll
        for (int q = 0; q < 8; ++q)
            a[q] = __half2float(beta[(size_t)(p[q] & 0x3FFFFu) * 32 + ch]);
#pragma unroll
        for (int q = 0; q < 8; ++q)
            atomicMax(&agg[(p[q] >> 18) * 32 + ch], enc(a[q]));
    }
    for (; e < cnt; e += 8) {
        unsigned p = P[e];
        float a = __half2float(beta[(size_t)(p & 0x3FFFFu) * 32 + ch]);
        atomicMax(&agg[(p >> 18) * 32 + ch], enc(a));
    }
    __syncthreads();

    // epilogue: BN+ReLU + voxel pool (sentinel u==0 -> no edges -> 0)
    int dbase = b * 256;
    for (int slot = threadIdx.x; slot < 8192; slot += 256) {
        int d = slot >> 5, n = dbase + d;
        unsigned u = agg[slot];
        float px = pos[3*n], py = pos[3*n+1], pz = pos[3*n+2];
        float v = u ? (dec(u) - (wrx*px + wry*py + wrz*pz)) : 0.0f;
        float y = fmaxf(v * sc + sh, 0.0f);
        int gx = (int)floorf(px * (1.0f/16.0f));
        int gy = (int)floorf(py * (1.0f/16.0f));
        int cl = min(max(gx + gy * 8, 0), 63);
        atomicMax(&lpool[cl * 32 + ch], enc(y));
    }
    __syncthreads();
    for (int i = threadIdx.x; i < 2048; i += 256) {
        unsigned u = lpool[i];
        if (u > pool[i]) atomicMax(&pool[i], u);
    }
}

__global__ __launch_bounds__(256) void pool_decode(const unsigned* __restrict__ pool,
                                                   float* __restrict__ out) {
    int i = blockIdx.x * 256 + threadIdx.x;   // 2048
    unsigned u = pool[i];
    out[i] = (u == 0u) ? 0.0f : dec(u);
}

extern "C" void kernel_launch(void* const* d_in, const int* in_sizes, int n_in,
                              void* d_out, int out_size, void* d_ws, size_t ws_size,
                              hipStream_t stream) {
    const float* x    = (const float*)d_in[0];
    const float* pos  = (const float*)d_in[1];
    const int*   ei   = (const int*)d_in[2];
    const float* W1   = (const float*)d_in[3];
    const float* b1   = (const float*)d_in[4];
    const float* bn1m = (const float*)d_in[5];
    const float* bn1v = (const float*)d_in[6];
    const float* bn1w = (const float*)d_in[7];
    const float* bn1b = (const float*)d_in[8];
    const float* W2   = (const float*)d_in[9];
    const float* b2   = (const float*)d_in[10];
    const float* bn2m = (const float*)d_in[11];
    const float* bn2v = (const float*)d_in[12];
    const float* bn2w = (const float*)d_in[13];
    const float* bn2b = (const float*)d_in[14];

    size_t N = N_NODES;
    unsigned* pool   = (unsigned*)d_ws;                   // 2048 [zeroed]
    int* bcur        = (int*)(pool + 2048);               // NBUCK [zeroed]
    unsigned* pairs2 = (unsigned*)(bcur + NBUCK);         // NBUCK*BCAP = 2.62M words
    float* px4       = (float*)(pairs2 + (size_t)NBUCK * BCAP); // 4N fp32 (4 MB)
    __half* beta     = (__half*)(px4 + 4 * N);            // 32N fp16 = 16N words

    hipMemsetAsync(d_ws, 0, (size_t)(2048 + NBUCK) * 4, stream);

    part_k      <<<PARTB, 256, 0, stream>>>(ei, bcur, pairs2, pos, x, (float4*)px4);
    conv1_push  <<<NBUCK, 256, 0, stream>>>((const float4*)px4, pos, pairs2, bcur,
                                            W1, b1, bn1m, bn1v, bn1w, bn1b, W2, b2, beta);
    conv2_push  <<<NBUCK, 256, 0, stream>>>(beta, pos, pairs2, bcur,
                                            W2, bn2m, bn2v, bn2w, bn2b, pool);
    pool_decode <<<8, 256, 0, stream>>>(pool, (float*)d_out);
}